// Round 10
// baseline (174.928 us; speedup 1.0000x reference)
//
#include <hip/hip_runtime.h>

// QLSTM: T=64, B=256, D=512, NQ=6.
// Closed form for _qlayer: with C_w = cos(x_w + theta_w):
//   z0 = C1*C2*C3*C4*C5, z1 = C0*C1, z2 = C0*C1*C2, z3 = C0..C3, z4 = C0..C4, z5 = C0..C5
//
// R10: FUSED producer-consumer kernel. R7-R9 showed gemm micro-structure is
// not the lever (all within 3us); gemm (~15-20us) and scan (~10-14us) were
// serialized + 2nd launch latency. Now: blocks 0..15 = scan (dispatched
// first -> resident, spinning on flags), blocks 16..1039 = gemm (R9 body,
// 16 rows each, 16 blocks per timestep t).
//   producer: syncthreads (drains stores) -> threadfence (L2 writeback,
//             cross-XCD) -> atomicAdd(done[t]).
//   consumer: every 8 steps spin done[t+2..t+9]==16 (relaxed agent atomic
//             + s_sleep), then one threadfence (L2 inv: kills stale lines
//             from previous replay's 0xAA poison). Deadlock-free: gemm
//             blocks never wait, queued blocks always drain.
// Flags in d_ws[0..63] zeroed via hipMemsetAsync (graph-capturable).
// gemm body (R9): k across lanes, 4 rows x 12 cols per wave (acc=48 VGPR,
//   launch_bounds(512,4) -> 16 waves/CU), W in LDS stride-25 (conflict-
//   free, ds_read2), quad-DPP reduce, static reg indexing only (R4 lesson).
// scan body (R8/R9): 4 thr/batch, DPP quad_perm exchange, pk_fma h@Wh,
//   polynomial activations (no v_exp), 2-deep prefetch.

typedef float v2f __attribute__((ext_vector_type(2)));

__device__ __forceinline__ float fast_rcp(float x) { return __builtin_amdgcn_rcpf(x); }

template <int CTRL>
__device__ __forceinline__ float dpp_add(float x) {
    int t = __builtin_amdgcn_mov_dpp(__float_as_int(x), CTRL, 0xF, 0xF, true);
    return x + __int_as_float(t);
}

template <int G>
__device__ __forceinline__ float quad_bcast(float v) {
    int i = __builtin_amdgcn_mov_dpp(__float_as_int(v), G * 0x55, 0xF, 0xF, true);
    return __int_as_float(i);
}

__global__ __launch_bounds__(512, 4) void qlstm_fused(
    const float* __restrict__ X,
    const float* __restrict__ Wf, const float* __restrict__ bf,
    const float* __restrict__ Wi, const float* __restrict__ bi,
    const float* __restrict__ Wu, const float* __restrict__ bu,
    const float* __restrict__ Wo, const float* __restrict__ bo,
    const float* __restrict__ thf, const float* __restrict__ thi,
    const float* __restrict__ thu, const float* __restrict__ tho,
    int* __restrict__ doneF, float* __restrict__ pre,
    float* __restrict__ out)
{
    __shared__ float W_lds[12800];
    const int bid = blockIdx.x;
    const int tid = threadIdx.x;

    if (bid >= 16) {
        // ================= GEMM role (R9 body) =================
        const int w    = tid >> 6;          // wave 0..7
        const int lane = tid & 63;
        const int rg   = w >> 1;            // row group 0..3 (4 rows each)
        const int cg   = w & 1;             // col half 0..1 (12 cols each)
        const int rowbase = (bid - 16) * 16;

        // ---- stage W into LDS (stride 25: odd -> all 32 banks) ----
        {
            const int k = tid;
            #pragma unroll
            for (int g = 0; g < 4; ++g) {
                const float* Wp = (g==0)?Wf:(g==1)?Wi:(g==2)?Wu:Wo;
                const float2* s = (const float2*)(Wp + k*6);
                float2 s0 = s[0], s1 = s[1], s2 = s[2];
                float* d = W_lds + k*25 + g*6;
                d[0] = s0.x; d[1] = s0.y; d[2] = s1.x;
                d[3] = s1.y; d[4] = s2.x; d[5] = s2.y;
            }
        }
        __syncthreads();

        // ---- main loop: 8 chunks of 64 k, register prefetch of A ----
        v2f acc[4][6];
        #pragma unroll
        for (int r = 0; r < 4; ++r)
            #pragma unroll
            for (int p = 0; p < 6; ++p) acc[r][p] = (v2f){0.f, 0.f};

        const float* Xr0 = X + (rowbase + rg*4)*512 + lane;
        const int colbase = cg*12;

        float pa[4];
        #pragma unroll
        for (int r = 0; r < 4; ++r) pa[r] = Xr0[r*512];

        #pragma unroll
        for (int kb = 0; kb < 512; kb += 64) {
            const float* Wrow = W_lds + (kb + lane)*25 + colbase;
            float a0 = pa[0], a1 = pa[1], a2 = pa[2], a3 = pa[3];
            if (kb < 448) {
                #pragma unroll
                for (int r = 0; r < 4; ++r) pa[r] = Xr0[kb + 64 + r*512];
            }
            #pragma unroll
            for (int p = 0; p < 6; ++p) {
                float wa = Wrow[p];
                float wb = Wrow[p + 6];     // ds_read2_b32, conflict-free
                v2f wv = (v2f){wa, wb};
                acc[0][p] = __builtin_elementwise_fma((v2f){a0,a0}, wv, acc[0][p]);
                acc[1][p] = __builtin_elementwise_fma((v2f){a1,a1}, wv, acc[1][p]);
                acc[2][p] = __builtin_elementwise_fma((v2f){a2,a2}, wv, acc[2][p]);
                acc[3][p] = __builtin_elementwise_fma((v2f){a3,a3}, wv, acc[3][p]);
            }
        }

        // ---- quad reduction: static indexing only ----
        #pragma unroll
        for (int r = 0; r < 4; ++r)
            #pragma unroll
            for (int p = 0; p < 6; ++p) {
                float x = acc[r][p].x;
                x = dpp_add<0xB1>(x);
                x = dpp_add<0x4E>(x);
                acc[r][p].x = x;
                float y = acc[r][p].y;
                y = dpp_add<0xB1>(y);
                y = dpp_add<0x4E>(y);
                acc[r][p].y = y;
            }

        #define ACCV(v) ((((v) % 12) < 6) ? acc[(v)/12][(v)%6].x \
                                          : acc[(v)/12][(v)%6].y)
        const int j = lane & 3;
        const int q = lane >> 2;
        const bool j1 = (j & 1) != 0, j2 = (j & 2) != 0;
        float sel[12];
        #pragma unroll
        for (int i = 0; i < 12; ++i) {
            float c0 = ACCV(i*4 + 0), c1 = ACCV(i*4 + 1);
            float c2 = ACCV(i*4 + 2), c3 = ACCV(i*4 + 3);
            float lo = j1 ? c1 : c0;
            float hi = j1 ? c3 : c2;
            sel[i] = j2 ? hi : lo;
        }
        #undef ACCV

        __syncthreads();
        #pragma unroll
        for (int i = 0; i < 12; ++i)
            W_lds[(w*48 + i*4 + j)*16 + q] = sel[i];
        __syncthreads();

        if (tid < 384) {
            int o = tid;
            int ww = o / 48, v = o - ww*48;
            int rr = v / 12, ph = v - rr*12;
            const float4* rp = (const float4*)(W_lds + (ww*48 + v)*16);
            float4 r0 = rp[0], r1 = rp[1], r2 = rp[2], r3 = rp[3];
            float s = ((r0.x+r0.y)+(r0.z+r0.w)) + ((r1.x+r1.y)+(r1.z+r1.w))
                    + ((r2.x+r2.y)+(r2.z+r2.w)) + ((r3.x+r3.y)+(r3.z+r3.w));
            int col = (ww & 1)*12 + ph;
            int g = col / 6, jg = col - g*6;
            const float* bb = (g==0)?bf:(g==1)?bi:(g==2)?bu:bo;
            const float* tt = (g==0)?thf:(g==1)?thi:(g==2)?thu:tho;
            s += bb[jg] + tt[jg];
            int row = rowbase + (ww >> 1)*4 + rr;
            pre[row*24 + col] = s;
        }

        // ---- signal: this block's 16 rows of timestep t are done ----
        __syncthreads();                 // drains vmcnt before barrier
        if (tid == 0) {
            __threadfence();             // L2 writeback (cross-XCD visibility)
            atomicAdd(&doneF[(bid - 16) >> 4], 1);
        }
        return;
    }

    // ================= SCAN role (blocks 0..15) =================
    if (tid >= 64) return;               // wave 0 only
    const int lane = tid;
    const int bl   = lane >> 2;
    const int g    = lane & 3;
    const int b    = bid * 16 + bl;

    const float* Wg = (g==0)?Wf:(g==1)?Wi:(g==2)?Wu:Wo;
    v2f Wh2[6][3];
    #pragma unroll
    for (int j = 0; j < 6; ++j)
        #pragma unroll
        for (int p = 0; p < 3; ++p)
            Wh2[j][p] = (v2f){Wg[(512 + j)*6 + 2*p], Wg[(512 + j)*6 + 2*p + 1]};

    const float c0 = (g==2) ? 0.f  : 0.5f;
    const float n0 = (g==2) ? 15.f : 0.25f;
    const float n1 = (g==2) ? 1.f  : -0.020833333f;
    const float n2 = (g==2) ? 0.f  : 0.0020833333f;
    const float d0 = (g==2) ? 15.f : 1.f;
    const float d1 = (g==2) ? 6.f  : 0.f;

    float h[6], c[6];
    #pragma unroll
    for (int w = 0; w < 6; ++w) { h[w] = 0.f; c[w] = 0.f; }

    // wait for timesteps 0..9 (covers initial loads + first 8 iterations)
    for (int tt = 0; tt <= 9; ++tt)
        while (__hip_atomic_load(doneF + tt, __ATOMIC_RELAXED,
                                 __HIP_MEMORY_SCOPE_AGENT) < 16)
            __builtin_amdgcn_s_sleep(2);
    __threadfence();                     // L2 invalidate: fresh pre reads

    const float* pb = pre + b*24 + g*6;
    v2f x0 = *(const v2f*)(pb);
    v2f x1 = *(const v2f*)(pb + 2);
    v2f x2 = *(const v2f*)(pb + 4);
    v2f n0v = *(const v2f*)(pb + 256*24);
    v2f n1v = *(const v2f*)(pb + 256*24 + 2);
    v2f n2v = *(const v2f*)(pb + 256*24 + 4);

    for (int t = 0; t < 64; ++t) {
        if ((t & 7) == 0 && t > 0) {     // batched wait for t+2 .. t+9
            int hi = t + 9; if (hi > 63) hi = 63;
            for (int tt = t + 2; tt <= hi; ++tt)
                while (__hip_atomic_load(doneF + tt, __ATOMIC_RELAXED,
                                         __HIP_MEMORY_SCOPE_AGENT) < 16)
                    __builtin_amdgcn_s_sleep(2);
            __threadfence();
        }

        v2f a2[3] = {x0, x1, x2};
        x0 = n0v; x1 = n1v; x2 = n2v;
        int tn = (t < 62) ? (t + 2) : 63;
        const float* pn = pre + (tn*256 + b)*24 + g*6;
        n0v = *(const v2f*)(pn);
        n1v = *(const v2f*)(pn + 2);
        n2v = *(const v2f*)(pn + 4);

        #pragma unroll
        for (int j = 0; j < 6; ++j) {
            v2f hj = (v2f){h[j], h[j]};
            #pragma unroll
            for (int p = 0; p < 3; ++p)
                a2[p] = __builtin_elementwise_fma(hj, Wh2[j][p], a2[p]);
        }

        float C[6];
        C[0] = __cosf(a2[0].x); C[1] = __cosf(a2[0].y);
        C[2] = __cosf(a2[1].x); C[3] = __cosf(a2[1].y);
        C[4] = __cosf(a2[2].x); C[5] = __cosf(a2[2].y);

        float p01 = C[0]*C[1], p23 = C[2]*C[3], p45 = C[4]*C[5];
        float z[6];
        z[1] = p01;
        z[2] = p01*C[2];
        z[3] = p01*p23;
        z[4] = z[3]*C[4];
        z[5] = z[3]*p45;
        z[0] = C[1]*(p23*p45);

        float act[6];
        #pragma unroll
        for (int w = 0; w < 6; ++w) {
            float y   = z[w]*z[w];
            float num = fmaf(y, fmaf(y, n2, n1), n0);
            float den = fmaf(y, d1, d0);
            act[w] = fmaf(z[w]*num, fast_rcp(den), c0);
        }

        float F[6], I[6], U[6], O[6];
        #pragma unroll
        for (int w = 0; w < 6; ++w) {
            F[w] = quad_bcast<0>(act[w]);
            I[w] = quad_bcast<1>(act[w]);
            U[w] = quad_bcast<2>(act[w]);
            O[w] = quad_bcast<3>(act[w]);
        }

        #pragma unroll
        for (int w = 0; w < 6; ++w) {
            c[w] = fmaf(F[w], c[w], I[w]*U[w]);
            float y   = c[w]*c[w];
            float num = fmaf(y, fmaf(y, 1.f, 105.f), 945.f);
            float den = fmaf(y, fmaf(y, 15.f, 420.f), 945.f);
            float tc  = c[w]*num*fast_rcp(den);
            h[w] = O[w]*tc;
        }

        if (g < 3) {
            float2 v;
            v.x = (g==0) ? h[0] : (g==1) ? h[2] : h[4];
            v.y = (g==0) ? h[1] : (g==1) ? h[3] : h[5];
            *(float2*)(out + (t*256 + b)*6 + g*2) = v;
        }
    }

    if (g < 3) {
        float2 v;
        v.x = (g==0) ? h[0] : (g==1) ? h[2] : h[4];
        v.y = (g==0) ? h[1] : (g==1) ? h[3] : h[5];
        *(float2*)(out + 64*256*6 + b*6 + g*2) = v;
        float2 u;
        u.x = (g==0) ? c[0] : (g==1) ? c[2] : c[4];
        u.y = (g==0) ? c[1] : (g==1) ? c[3] : c[5];
        *(float2*)(out + 64*256*6 + 256*6 + b*6 + g*2) = u;
    }
}

extern "C" void kernel_launch(void* const* d_in, const int* in_sizes, int n_in,
                              void* d_out, int out_size, void* d_ws, size_t ws_size,
                              hipStream_t stream) {
    const float* X   = (const float*)d_in[0];
    const float* Wf  = (const float*)d_in[1];
    const float* bf_ = (const float*)d_in[2];
    const float* Wi  = (const float*)d_in[3];
    const float* bi_ = (const float*)d_in[4];
    const float* Wu  = (const float*)d_in[5];
    const float* bu_ = (const float*)d_in[6];
    const float* Wo  = (const float*)d_in[7];
    const float* bo_ = (const float*)d_in[8];
    const float* thf = (const float*)d_in[9];
    const float* thi = (const float*)d_in[10];
    const float* thu = (const float*)d_in[11];
    const float* tho = (const float*)d_in[12];

    int*   doneF = (int*)d_ws;             // 64 flags (256 B)
    float* pre   = (float*)d_ws + 64;      // 16384*24 floats
    float* out   = (float*)d_out;

    hipMemsetAsync(d_ws, 0, 256, stream);  // zero flags (ws is poisoned 0xAA)
    qlstm_fused<<<1040, 512, 0, stream>>>(X, Wf, bf_, Wi, bi_, Wu, bu_,
                                          Wo, bo_, thf, thi, thu, tho,
                                          doneF, pre, out);
}

// Round 11
// 153.426 us; speedup vs baseline: 1.1401x; 1.1401x over previous
//
#include <hip/hip_runtime.h>

// QLSTM: T=64, B=256, D=512, NQ=6.
// Closed form for _qlayer: with C_w = cos(x_w + theta_w):
//   z0 = C1*C2*C3*C4*C5, z1 = C0*C1, z2 = C0*C1*C2, z3 = C0..C3, z4 = C0..C4, z5 = C0..C5
//
// R11: fused producer-consumer, FENCE-FREE handshake. R10's __threadfence()
// (buffer_wbl2 + buffer_inv per call, 1024+ calls) caused an L2 writeback/
// invalidate storm -> 94us kernel at 7% VALU. Now all cross-XCD traffic
// uses agent-scope relaxed atomics (sc1: bypass per-XCD L2, complete at
// the die-level L3 coherence point):
//   producer: pre stores = relaxed agent atomic stores (1 dword/thread,
//     same count as before); __syncthreads() drains every thread's vmcnt
//     -> globally visible; tid0 relaxed agent fetch_add on done[t].
//   consumer: polls done[] and reads pre[] with relaxed agent loads.
//   NO fences anywhere. Gemm's X reads keep normal caching.
// Deadlock-free: producers never wait; consumer blocks (0..15) dispatched
// first, spin with s_sleep.
// gemm body (R9): k across lanes, 4 rows x 12 cols per wave (acc=48 VGPR),
//   W in LDS stride-25 (conflict-free, ds_read2), quad-DPP reduce, static
//   reg indexing only (R4 lesson: dynamic reg idx -> scratch spill).
// scan body (R8): 4 thr/batch, DPP quad_perm exchange, pk_fma h@Wh,
//   polynomial activations (no v_exp), 2-deep prefetch.

typedef float v2f __attribute__((ext_vector_type(2)));

__device__ __forceinline__ float fast_rcp(float x) { return __builtin_amdgcn_rcpf(x); }

__device__ __forceinline__ void store_l3(float* p, float v) {
    __hip_atomic_store((unsigned int*)p, __float_as_uint(v),
                       __ATOMIC_RELAXED, __HIP_MEMORY_SCOPE_AGENT);
}
__device__ __forceinline__ float load_l3(const float* p) {
    unsigned int u = __hip_atomic_load((const unsigned int*)p,
                                       __ATOMIC_RELAXED, __HIP_MEMORY_SCOPE_AGENT);
    return __uint_as_float(u);
}

template <int CTRL>
__device__ __forceinline__ float dpp_add(float x) {
    int t = __builtin_amdgcn_mov_dpp(__float_as_int(x), CTRL, 0xF, 0xF, true);
    return x + __int_as_float(t);
}

template <int G>
__device__ __forceinline__ float quad_bcast(float v) {
    int i = __builtin_amdgcn_mov_dpp(__float_as_int(v), G * 0x55, 0xF, 0xF, true);
    return __int_as_float(i);
}

__global__ __launch_bounds__(512, 4) void qlstm_fused(
    const float* __restrict__ X,
    const float* __restrict__ Wf, const float* __restrict__ bf,
    const float* __restrict__ Wi, const float* __restrict__ bi,
    const float* __restrict__ Wu, const float* __restrict__ bu,
    const float* __restrict__ Wo, const float* __restrict__ bo,
    const float* __restrict__ thf, const float* __restrict__ thi,
    const float* __restrict__ thu, const float* __restrict__ tho,
    int* __restrict__ doneF, float* __restrict__ pre,
    float* __restrict__ out)
{
    __shared__ float W_lds[12800];
    const int bid = blockIdx.x;
    const int tid = threadIdx.x;

    if (bid >= 16) {
        // ================= GEMM role (R9 body) =================
        const int w    = tid >> 6;          // wave 0..7
        const int lane = tid & 63;
        const int rg   = w >> 1;            // row group 0..3 (4 rows each)
        const int cg   = w & 1;             // col half 0..1 (12 cols each)
        const int rowbase = (bid - 16) * 16;

        // ---- stage W into LDS (stride 25: odd -> all 32 banks) ----
        {
            const int k = tid;
            #pragma unroll
            for (int g = 0; g < 4; ++g) {
                const float* Wp = (g==0)?Wf:(g==1)?Wi:(g==2)?Wu:Wo;
                const float2* s = (const float2*)(Wp + k*6);
                float2 s0 = s[0], s1 = s[1], s2 = s[2];
                float* d = W_lds + k*25 + g*6;
                d[0] = s0.x; d[1] = s0.y; d[2] = s1.x;
                d[3] = s1.y; d[4] = s2.x; d[5] = s2.y;
            }
        }
        __syncthreads();

        // ---- main loop: 8 chunks of 64 k, register prefetch of A ----
        v2f acc[4][6];
        #pragma unroll
        for (int r = 0; r < 4; ++r)
            #pragma unroll
            for (int p = 0; p < 6; ++p) acc[r][p] = (v2f){0.f, 0.f};

        const float* Xr0 = X + (rowbase + rg*4)*512 + lane;
        const int colbase = cg*12;

        float pa[4];
        #pragma unroll
        for (int r = 0; r < 4; ++r) pa[r] = Xr0[r*512];

        #pragma unroll
        for (int kb = 0; kb < 512; kb += 64) {
            const float* Wrow = W_lds + (kb + lane)*25 + colbase;
            float a0 = pa[0], a1 = pa[1], a2 = pa[2], a3 = pa[3];
            if (kb < 448) {
                #pragma unroll
                for (int r = 0; r < 4; ++r) pa[r] = Xr0[kb + 64 + r*512];
            }
            #pragma unroll
            for (int p = 0; p < 6; ++p) {
                float wa = Wrow[p];
                float wb = Wrow[p + 6];     // ds_read2_b32, conflict-free
                v2f wv = (v2f){wa, wb};
                acc[0][p] = __builtin_elementwise_fma((v2f){a0,a0}, wv, acc[0][p]);
                acc[1][p] = __builtin_elementwise_fma((v2f){a1,a1}, wv, acc[1][p]);
                acc[2][p] = __builtin_elementwise_fma((v2f){a2,a2}, wv, acc[2][p]);
                acc[3][p] = __builtin_elementwise_fma((v2f){a3,a3}, wv, acc[3][p]);
            }
        }

        // ---- quad reduction: static indexing only ----
        #pragma unroll
        for (int r = 0; r < 4; ++r)
            #pragma unroll
            for (int p = 0; p < 6; ++p) {
                float x = acc[r][p].x;
                x = dpp_add<0xB1>(x);
                x = dpp_add<0x4E>(x);
                acc[r][p].x = x;
                float y = acc[r][p].y;
                y = dpp_add<0xB1>(y);
                y = dpp_add<0x4E>(y);
                acc[r][p].y = y;
            }

        #define ACCV(v) ((((v) % 12) < 6) ? acc[(v)/12][(v)%6].x \
                                          : acc[(v)/12][(v)%6].y)
        const int j = lane & 3;
        const int q = lane >> 2;
        const bool j1 = (j & 1) != 0, j2 = (j & 2) != 0;
        float sel[12];
        #pragma unroll
        for (int i = 0; i < 12; ++i) {
            float c0 = ACCV(i*4 + 0), c1 = ACCV(i*4 + 1);
            float c2 = ACCV(i*4 + 2), c3 = ACCV(i*4 + 3);
            float lo = j1 ? c1 : c0;
            float hi = j1 ? c3 : c2;
            sel[i] = j2 ? hi : lo;
        }
        #undef ACCV

        __syncthreads();
        #pragma unroll
        for (int i = 0; i < 12; ++i)
            W_lds[(w*48 + i*4 + j)*16 + q] = sel[i];
        __syncthreads();

        if (tid < 384) {
            int o = tid;
            int ww = o / 48, v = o - ww*48;
            int rr = v / 12, ph = v - rr*12;
            const float4* rp = (const float4*)(W_lds + (ww*48 + v)*16);
            float4 r0 = rp[0], r1 = rp[1], r2 = rp[2], r3 = rp[3];
            float s = ((r0.x+r0.y)+(r0.z+r0.w)) + ((r1.x+r1.y)+(r1.z+r1.w))
                    + ((r2.x+r2.y)+(r2.z+r2.w)) + ((r3.x+r3.y)+(r3.z+r3.w));
            int col = (ww & 1)*12 + ph;
            int g = col / 6, jg = col - g*6;
            const float* bb = (g==0)?bf:(g==1)?bi:(g==2)?bu:bo;
            const float* tt = (g==0)?thf:(g==1)?thi:(g==2)?thu:tho;
            s += bb[jg] + tt[jg];
            int row = rowbase + (ww >> 1)*4 + rr;
            store_l3(&pre[row*24 + col], s);   // sc1: straight to L3, no L2 dirt
        }

        // ---- signal: __syncthreads drains ALL threads' vmcnt -> stores
        //      globally visible (sc1 completion = coherence point) ----
        __syncthreads();
        if (tid == 0)
            __hip_atomic_fetch_add(&doneF[(bid - 16) >> 4], 1,
                                   __ATOMIC_RELAXED, __HIP_MEMORY_SCOPE_AGENT);
        return;
    }

    // ================= SCAN role (blocks 0..15) =================
    if (tid >= 64) return;               // wave 0 only
    const int lane = tid;
    const int bl   = lane >> 2;
    const int g    = lane & 3;
    const int b    = bid * 16 + bl;

    const float* Wg = (g==0)?Wf:(g==1)?Wi:(g==2)?Wu:Wo;
    v2f Wh2[6][3];
    #pragma unroll
    for (int j = 0; j < 6; ++j)
        #pragma unroll
        for (int p = 0; p < 3; ++p)
            Wh2[j][p] = (v2f){Wg[(512 + j)*6 + 2*p], Wg[(512 + j)*6 + 2*p + 1]};

    const float c0 = (g==2) ? 0.f  : 0.5f;
    const float n0 = (g==2) ? 15.f : 0.25f;
    const float n1 = (g==2) ? 1.f  : -0.020833333f;
    const float n2 = (g==2) ? 0.f  : 0.0020833333f;
    const float d0 = (g==2) ? 15.f : 1.f;
    const float d1 = (g==2) ? 6.f  : 0.f;

    float h[6], c[6];
    #pragma unroll
    for (int w = 0; w < 6; ++w) { h[w] = 0.f; c[w] = 0.f; }

    // wait for timesteps 0..9 (covers initial loads + first 8 iterations)
    for (int tt = 0; tt <= 9; ++tt)
        while (__hip_atomic_load(doneF + tt, __ATOMIC_RELAXED,
                                 __HIP_MEMORY_SCOPE_AGENT) < 16)
            __builtin_amdgcn_s_sleep(2);

    const float* pb = pre + b*24 + g*6;
    float xc[6], xn[6];
    #pragma unroll
    for (int i = 0; i < 6; ++i) {
        xc[i] = load_l3(pb + i);
        xn[i] = load_l3(pb + 256*24 + i);
    }

    for (int t = 0; t < 64; ++t) {
        if ((t & 7) == 0 && t > 0) {     // batched wait for t+2 .. t+9
            int hi = t + 9; if (hi > 63) hi = 63;
            for (int tt = t + 2; tt <= hi; ++tt)
                while (__hip_atomic_load(doneF + tt, __ATOMIC_RELAXED,
                                         __HIP_MEMORY_SCOPE_AGENT) < 16)
                    __builtin_amdgcn_s_sleep(2);
        }

        v2f a2[3] = {(v2f){xc[0], xc[1]}, (v2f){xc[2], xc[3]}, (v2f){xc[4], xc[5]}};
        #pragma unroll
        for (int i = 0; i < 6; ++i) xc[i] = xn[i];
        int tn = (t < 62) ? (t + 2) : 63;
        const float* pn = pre + (tn*256 + b)*24 + g*6;
        #pragma unroll
        for (int i = 0; i < 6; ++i) xn[i] = load_l3(pn + i);

        #pragma unroll
        for (int j = 0; j < 6; ++j) {
            v2f hj = (v2f){h[j], h[j]};
            #pragma unroll
            for (int p = 0; p < 3; ++p)
                a2[p] = __builtin_elementwise_fma(hj, Wh2[j][p], a2[p]);
        }

        float C[6];
        C[0] = __cosf(a2[0].x); C[1] = __cosf(a2[0].y);
        C[2] = __cosf(a2[1].x); C[3] = __cosf(a2[1].y);
        C[4] = __cosf(a2[2].x); C[5] = __cosf(a2[2].y);

        float p01 = C[0]*C[1], p23 = C[2]*C[3], p45 = C[4]*C[5];
        float z[6];
        z[1] = p01;
        z[2] = p01*C[2];
        z[3] = p01*p23;
        z[4] = z[3]*C[4];
        z[5] = z[3]*p45;
        z[0] = C[1]*(p23*p45);

        float act[6];
        #pragma unroll
        for (int w = 0; w < 6; ++w) {
            float y   = z[w]*z[w];
            float num = fmaf(y, fmaf(y, n2, n1), n0);
            float den = fmaf(y, d1, d0);
            act[w] = fmaf(z[w]*num, fast_rcp(den), c0);
        }

        float F[6], I[6], U[6], O[6];
        #pragma unroll
        for (int w = 0; w < 6; ++w) {
            F[w] = quad_bcast<0>(act[w]);
            I[w] = quad_bcast<1>(act[w]);
            U[w] = quad_bcast<2>(act[w]);
            O[w] = quad_bcast<3>(act[w]);
        }

        #pragma unroll
        for (int w = 0; w < 6; ++w) {
            c[w] = fmaf(F[w], c[w], I[w]*U[w]);
            float y   = c[w]*c[w];
            float num = fmaf(y, fmaf(y, 1.f, 105.f), 945.f);
            float den = fmaf(y, fmaf(y, 15.f, 420.f), 945.f);
            float tc  = c[w]*num*fast_rcp(den);
            h[w] = O[w]*tc;
        }

        if (g < 3) {
            float2 v;
            v.x = (g==0) ? h[0] : (g==1) ? h[2] : h[4];
            v.y = (g==0) ? h[1] : (g==1) ? h[3] : h[5];
            *(float2*)(out + (t*256 + b)*6 + g*2) = v;
        }
    }

    if (g < 3) {
        float2 v;
        v.x = (g==0) ? h[0] : (g==1) ? h[2] : h[4];
        v.y = (g==0) ? h[1] : (g==1) ? h[3] : h[5];
        *(float2*)(out + 64*256*6 + b*6 + g*2) = v;
        float2 u;
        u.x = (g==0) ? c[0] : (g==1) ? c[2] : c[4];
        u.y = (g==0) ? c[1] : (g==1) ? c[3] : c[5];
        *(float2*)(out + 64*256*6 + 256*6 + b*6 + g*2) = u;
    }
}

extern "C" void kernel_launch(void* const* d_in, const int* in_sizes, int n_in,
                              void* d_out, int out_size, void* d_ws, size_t ws_size,
                              hipStream_t stream) {
    const float* X   = (const float*)d_in[0];
    const float* Wf  = (const float*)d_in[1];
    const float* bf_ = (const float*)d_in[2];
    const float* Wi  = (const float*)d_in[3];
    const float* bi_ = (const float*)d_in[4];
    const float* Wu  = (const float*)d_in[5];
    const float* bu_ = (const float*)d_in[6];
    const float* Wo  = (const float*)d_in[7];
    const float* bo_ = (const float*)d_in[8];
    const float* thf = (const float*)d_in[9];
    const float* thi = (const float*)d_in[10];
    const float* thu = (const float*)d_in[11];
    const float* tho = (const float*)d_in[12];

    int*   doneF = (int*)d_ws;             // 64 flags (256 B)
    float* pre   = (float*)d_ws + 64;      // 16384*24 floats
    float* out   = (float*)d_out;

    hipMemsetAsync(d_ws, 0, 256, stream);  // zero flags (ws is poisoned 0xAA)
    qlstm_fused<<<1040, 512, 0, stream>>>(X, Wf, bf_, Wi, bi_, Wu, bu_,
                                          Wo, bo_, thf, thi, thu, tho,
                                          doneF, pre, out);
}

// Round 12
// 135.617 us; speedup vs baseline: 1.2899x; 1.1313x over previous
//
#include <hip/hip_runtime.h>

// QLSTM: T=64, B=256, D=512, NQ=6.
// Closed form for _qlayer: with C_w = cos(x_w + theta_w):
//   z0 = C1*C2*C3*C4*C5, z1 = C0*C1, z2 = C0*C1*C2, z3 = C0..C3, z4 = C0..C4, z5 = C0..C5
//
// R12: two-kernel form (R10/R11 fused producer-consumer REGRESSED: fence
// storm 94us / sc1-atomic path 65us vs ~30us serial pair -- reverted).
// gemm_pre: R9 body + ALL A loads hoisted ahead of the k-loop:
//   each lane's footprint is 32 dwords (8 chunks x 4 rows); all 32
//   independent loads issue before the W-staging barrier; the compiler's
//   vmcnt(0) drain at __syncthreads pays the ~600cyc L3 latency ONCE,
//   and the 8-chunk FMA/LDS loop runs with zero VMEM stalls.
//   (R5-R9 paid ~450cyc stall per chunk: 1-chunk prefetch < L3 latency.)
//   - k across lanes, 4 rows x 12 cols per wave, acc=48 VGPR, total ~110
//     -> launch_bounds(512,4) keeps 4 waves/SIMD.
//   - W in LDS stride-25 (odd -> all 32 banks conflict-free), ds_read2
//     pair reads (c, c+6).
//   - quad-DPP reduce; static register indexing ONLY (R4 lesson: dynamic
//     reg indexing -> scratch spill, 845 MB traffic).
// qlstm_scan (R8/R9): 4 thr/batch, DPP quad_perm exchange, pk_fma h@Wh,
//   polynomial activations (no v_exp), 2-deep prefetch.

typedef float v2f __attribute__((ext_vector_type(2)));

__device__ __forceinline__ float fast_rcp(float x) { return __builtin_amdgcn_rcpf(x); }

template <int CTRL>
__device__ __forceinline__ float dpp_add(float x) {
    int t = __builtin_amdgcn_mov_dpp(__float_as_int(x), CTRL, 0xF, 0xF, true);
    return x + __int_as_float(t);
}

template <int G>
__device__ __forceinline__ float quad_bcast(float v) {
    int i = __builtin_amdgcn_mov_dpp(__float_as_int(v), G * 0x55, 0xF, 0xF, true);
    return __int_as_float(i);
}

__global__ __launch_bounds__(512, 4) void gemm_pre(
    const float* __restrict__ X,
    const float* __restrict__ Wf, const float* __restrict__ bf,
    const float* __restrict__ Wi, const float* __restrict__ bi,
    const float* __restrict__ Wu, const float* __restrict__ bu,
    const float* __restrict__ Wo, const float* __restrict__ bo,
    const float* __restrict__ thf, const float* __restrict__ thi,
    const float* __restrict__ thu, const float* __restrict__ tho,
    float* __restrict__ pre)
{
    // W_lds[k*25 + c]; 512*25 = 12800 floats. Epilogue overlays 6144.
    __shared__ float W_lds[12800];

    const int tid  = threadIdx.x;
    const int w    = tid >> 6;          // wave 0..7
    const int lane = tid & 63;
    const int rg   = w >> 1;            // row group 0..3 (4 rows each)
    const int cg   = w & 1;             // col half 0..1 (12 cols each)
    const int rowbase = blockIdx.x * 16;

    // ---- issue ALL 32 A loads first (independent, fill the VMEM queue) ----
    const float* Xr0 = X + (rowbase + rg*4)*512 + lane;
    float pa[8][4];
    #pragma unroll
    for (int cny = 0; cny < 8; ++cny)
        #pragma unroll
        for (int r = 0; r < 4; ++r)
            pa[cny][r] = Xr0[cny*64 + r*512];

    // ---- stage W into LDS (overlaps the A loads' latency) ----
    {
        const int k = tid;
        #pragma unroll
        for (int g = 0; g < 4; ++g) {
            const float* Wp = (g==0)?Wf:(g==1)?Wi:(g==2)?Wu:Wo;
            const float2* s = (const float2*)(Wp + k*6);
            float2 s0 = s[0], s1 = s[1], s2 = s[2];
            float* d = W_lds + k*25 + g*6;
            d[0] = s0.x; d[1] = s0.y; d[2] = s1.x;
            d[3] = s1.y; d[4] = s2.x; d[5] = s2.y;
        }
    }
    __syncthreads();   // vmcnt(0) drain: pays A latency once, here

    // ---- main loop: 8 chunks of 64 k, zero VMEM stalls ----
    v2f acc[4][6];
    #pragma unroll
    for (int r = 0; r < 4; ++r)
        #pragma unroll
        for (int p = 0; p < 6; ++p) acc[r][p] = (v2f){0.f, 0.f};

    const int colbase = cg*12;

    #pragma unroll
    for (int cny = 0; cny < 8; ++cny) {
        const float* Wrow = W_lds + (cny*64 + lane)*25 + colbase;
        float a0 = pa[cny][0], a1 = pa[cny][1], a2 = pa[cny][2], a3 = pa[cny][3];
        #pragma unroll
        for (int p = 0; p < 6; ++p) {
            float wa = Wrow[p];
            float wb = Wrow[p + 6];     // ds_read2_b32, conflict-free
            v2f wv = (v2f){wa, wb};
            acc[0][p] = __builtin_elementwise_fma((v2f){a0,a0}, wv, acc[0][p]);
            acc[1][p] = __builtin_elementwise_fma((v2f){a1,a1}, wv, acc[1][p]);
            acc[2][p] = __builtin_elementwise_fma((v2f){a2,a2}, wv, acc[2][p]);
            acc[3][p] = __builtin_elementwise_fma((v2f){a3,a3}, wv, acc[3][p]);
        }
    }

    // ---- quad reduction: static indexing only ----
    #pragma unroll
    for (int r = 0; r < 4; ++r)
        #pragma unroll
        for (int p = 0; p < 6; ++p) {
            float x = acc[r][p].x;
            x = dpp_add<0xB1>(x);
            x = dpp_add<0x4E>(x);
            acc[r][p].x = x;
            float y = acc[r][p].y;
            y = dpp_add<0xB1>(y);
            y = dpp_add<0x4E>(y);
            acc[r][p].y = y;
        }

    // flat v = r*12 + ph, ph = p + 6*e  ->  acc[v/12][v%6].{x if ph<6 else y}
    #define ACCV(v) ((((v) % 12) < 6) ? acc[(v)/12][(v)%6].x \
                                      : acc[(v)/12][(v)%6].y)
    const int j = lane & 3;
    const int q = lane >> 2;
    const bool j1 = (j & 1) != 0, j2 = (j & 2) != 0;
    float sel[12];
    #pragma unroll
    for (int i = 0; i < 12; ++i) {
        float c0 = ACCV(i*4 + 0), c1 = ACCV(i*4 + 1);
        float c2 = ACCV(i*4 + 2), c3 = ACCV(i*4 + 3);
        float lo = j1 ? c1 : c0;
        float hi = j1 ? c3 : c2;
        sel[i] = j2 ? hi : lo;
    }
    #undef ACCV

    __syncthreads();                    // everyone done reading W_lds
    #pragma unroll
    for (int i = 0; i < 12; ++i)
        W_lds[(w*48 + i*4 + j)*16 + q] = sel[i];
    __syncthreads();

    // ---- final: 384 outputs per block (8 waves * 4 rows * 12 cols) ----
    if (tid < 384) {
        int o = tid;
        int ww = o / 48, v = o - ww*48;
        int rr = v / 12, ph = v - rr*12;
        const float4* rp = (const float4*)(W_lds + (ww*48 + v)*16);
        float4 r0 = rp[0], r1 = rp[1], r2 = rp[2], r3 = rp[3];
        float s = ((r0.x+r0.y)+(r0.z+r0.w)) + ((r1.x+r1.y)+(r1.z+r1.w))
                + ((r2.x+r2.y)+(r2.z+r2.w)) + ((r3.x+r3.y)+(r3.z+r3.w));
        int col = (ww & 1)*12 + ph;
        int g = col / 6, jg = col - g*6;
        const float* bb = (g==0)?bf:(g==1)?bi:(g==2)?bu:bo;
        const float* tt = (g==0)?thf:(g==1)?thi:(g==2)?thu:tho;
        s += bb[jg] + tt[jg];
        int row = rowbase + (ww >> 1)*4 + rr;
        pre[row*24 + col] = s;
    }
}

__global__ __launch_bounds__(64, 1) void qlstm_scan(
    const float* __restrict__ pre,
    const float* __restrict__ Wf, const float* __restrict__ Wi,
    const float* __restrict__ Wu, const float* __restrict__ Wo,
    float* __restrict__ out)
{
    // 4 threads per batch element (one per gate), one aligned hw quad per batch.
    const int lane = threadIdx.x;
    const int bl   = lane >> 2;
    const int g    = lane & 3;
    const int b    = blockIdx.x * 16 + bl;

    const float* Wg = (g==0)?Wf:(g==1)?Wi:(g==2)?Wu:Wo;
    v2f Wh2[6][3];
    #pragma unroll
    for (int j = 0; j < 6; ++j)
        #pragma unroll
        for (int p = 0; p < 3; ++p)
            Wh2[j][p] = (v2f){Wg[(512 + j)*6 + 2*p], Wg[(512 + j)*6 + 2*p + 1]};

    const float c0 = (g==2) ? 0.f  : 0.5f;
    const float n0 = (g==2) ? 15.f : 0.25f;
    const float n1 = (g==2) ? 1.f  : -0.020833333f;
    const float n2 = (g==2) ? 0.f  : 0.0020833333f;
    const float d0 = (g==2) ? 15.f : 1.f;
    const float d1 = (g==2) ? 6.f  : 0.f;

    float h[6], c[6];
    #pragma unroll
    for (int w = 0; w < 6; ++w) { h[w] = 0.f; c[w] = 0.f; }

    // 2-step-deep prefetch of pre
    const float* pb = pre + b*24 + g*6;
    v2f x0 = *(const v2f*)(pb);
    v2f x1 = *(const v2f*)(pb + 2);
    v2f x2 = *(const v2f*)(pb + 4);
    v2f n0v = *(const v2f*)(pb + 256*24);
    v2f n1v = *(const v2f*)(pb + 256*24 + 2);
    v2f n2v = *(const v2f*)(pb + 256*24 + 4);

    for (int t = 0; t < 64; ++t) {
        v2f a2[3] = {x0, x1, x2};
        x0 = n0v; x1 = n1v; x2 = n2v;
        int tn = (t < 62) ? (t + 2) : 63;
        const float* pn = pre + (tn*256 + b)*24 + g*6;
        n0v = *(const v2f*)(pn);
        n1v = *(const v2f*)(pn + 2);
        n2v = *(const v2f*)(pn + 4);

        #pragma unroll
        for (int j = 0; j < 6; ++j) {
            v2f hj = (v2f){h[j], h[j]};
            #pragma unroll
            for (int p = 0; p < 3; ++p)
                a2[p] = __builtin_elementwise_fma(hj, Wh2[j][p], a2[p]);
        }

        float C[6];
        C[0] = __cosf(a2[0].x); C[1] = __cosf(a2[0].y);
        C[2] = __cosf(a2[1].x); C[3] = __cosf(a2[1].y);
        C[4] = __cosf(a2[2].x); C[5] = __cosf(a2[2].y);

        float p01 = C[0]*C[1], p23 = C[2]*C[3], p45 = C[4]*C[5];
        float z[6];
        z[1] = p01;
        z[2] = p01*C[2];
        z[3] = p01*p23;
        z[4] = z[3]*C[4];
        z[5] = z[3]*p45;
        z[0] = C[1]*(p23*p45);

        float act[6];
        #pragma unroll
        for (int w = 0; w < 6; ++w) {
            float y   = z[w]*z[w];
            float num = fmaf(y, fmaf(y, n2, n1), n0);
            float den = fmaf(y, d1, d0);
            act[w] = fmaf(z[w]*num, fast_rcp(den), c0);
        }

        float F[6], I[6], U[6], O[6];
        #pragma unroll
        for (int w = 0; w < 6; ++w) {
            F[w] = quad_bcast<0>(act[w]);
            I[w] = quad_bcast<1>(act[w]);
            U[w] = quad_bcast<2>(act[w]);
            O[w] = quad_bcast<3>(act[w]);
        }

        #pragma unroll
        for (int w = 0; w < 6; ++w) {
            c[w] = fmaf(F[w], c[w], I[w]*U[w]);
            float y   = c[w]*c[w];
            float num = fmaf(y, fmaf(y, 1.f, 105.f), 945.f);
            float den = fmaf(y, fmaf(y, 15.f, 420.f), 945.f);
            float tc  = c[w]*num*fast_rcp(den);
            h[w] = O[w]*tc;
        }

        if (g < 3) {
            float2 v;
            v.x = (g==0) ? h[0] : (g==1) ? h[2] : h[4];
            v.y = (g==0) ? h[1] : (g==1) ? h[3] : h[5];
            *(float2*)(out + (t*256 + b)*6 + g*2) = v;
        }
    }

    if (g < 3) {
        float2 v;
        v.x = (g==0) ? h[0] : (g==1) ? h[2] : h[4];
        v.y = (g==0) ? h[1] : (g==1) ? h[3] : h[5];
        *(float2*)(out + 64*256*6 + b*6 + g*2) = v;
        float2 u;
        u.x = (g==0) ? c[0] : (g==1) ? c[2] : c[4];
        u.y = (g==0) ? c[1] : (g==1) ? c[3] : c[5];
        *(float2*)(out + 64*256*6 + 256*6 + b*6 + g*2) = u;
    }
}

extern "C" void kernel_launch(void* const* d_in, const int* in_sizes, int n_in,
                              void* d_out, int out_size, void* d_ws, size_t ws_size,
                              hipStream_t stream) {
    const float* X   = (const float*)d_in[0];
    const float* Wf  = (const float*)d_in[1];
    const float* bf_ = (const float*)d_in[2];
    const float* Wi  = (const float*)d_in[3];
    const float* bi_ = (const float*)d_in[4];
    const float* Wu  = (const float*)d_in[5];
    const float* bu_ = (const float*)d_in[6];
    const float* Wo  = (const float*)d_in[7];
    const float* bo_ = (const float*)d_in[8];
    const float* thf = (const float*)d_in[9];
    const float* thi = (const float*)d_in[10];
    const float* thu = (const float*)d_in[11];
    const float* tho = (const float*)d_in[12];

    float* pre = (float*)d_ws;           // 16384*24 floats = 1.57 MB
    float* out = (float*)d_out;

    gemm_pre<<<1024, 512, 0, stream>>>(X, Wf, bf_, Wi, bi_, Wu, bu_, Wo, bo_,
                                       thf, thi, thu, tho, pre);
    qlstm_scan<<<16, 64, 0, stream>>>(pre, Wf, Wi, Wu, Wo, out);
}

// Round 13
// 134.708 us; speedup vs baseline: 1.2986x; 1.0067x over previous
//
#include <hip/hip_runtime.h>

// QLSTM: T=64, B=256, D=512, NQ=6.
// Closed form for _qlayer: with C_w = cos(x_w + theta_w):
//   z0 = C1*C2*C3*C4*C5, z1 = C0*C1, z2 = C0*C1*C2, z3 = C0..C3, z4 = C0..C4, z5 = C0..C5
//
// R13: two-kernel form (fused variants R10/R11 regressed). Cross-round
// accounting shows harness restore/poison fills OVERLAP our kernels
// (derived fixed cost shrinks 118->80 as kernel time grows) -> dur
// asymptotes to the fill chain; remaining controllable ~10-15us.
// gemm_pre (R12 + coalesced W staging): A loads hoisted (32 dwords/lane
//   before the barrier, latency paid once); W staged via FLAT float2
//   loads (consecutive lanes -> 2-line span vs 24-line span of the old
//   stride-24B pattern; kills texture-unit transaction amplification),
//   LDS scatter via magic div-3. W_lds stride-25 (conflict-free),
//   ds_read2 pair reads, quad-DPP reduce, static reg indexing ONLY.
// qlstm_scan (R8 + v2f packing): activation poly, c-update, tanh(c) in
//   v_pk_fma_f32 (~180 -> ~135 inst/step); DPP quad_perm exchange;
//   polynomial activations (no v_exp); 2-deep prefetch.

typedef float v2f __attribute__((ext_vector_type(2)));

__device__ __forceinline__ float fast_rcp(float x) { return __builtin_amdgcn_rcpf(x); }

template <int CTRL>
__device__ __forceinline__ float dpp_add(float x) {
    int t = __builtin_amdgcn_mov_dpp(__float_as_int(x), CTRL, 0xF, 0xF, true);
    return x + __int_as_float(t);
}

template <int G>
__device__ __forceinline__ float quad_bcast(float v) {
    int i = __builtin_amdgcn_mov_dpp(__float_as_int(v), G * 0x55, 0xF, 0xF, true);
    return __int_as_float(i);
}

__global__ __launch_bounds__(512, 4) void gemm_pre(
    const float* __restrict__ X,
    const float* __restrict__ Wf, const float* __restrict__ bf,
    const float* __restrict__ Wi, const float* __restrict__ bi,
    const float* __restrict__ Wu, const float* __restrict__ bu,
    const float* __restrict__ Wo, const float* __restrict__ bo,
    const float* __restrict__ thf, const float* __restrict__ thi,
    const float* __restrict__ thu, const float* __restrict__ tho,
    float* __restrict__ pre)
{
    // W_lds[k*25 + c]; 512*25 = 12800 floats. Epilogue overlays 6144.
    __shared__ float W_lds[12800];

    const int tid  = threadIdx.x;
    const int w    = tid >> 6;          // wave 0..7
    const int lane = tid & 63;
    const int rg   = w >> 1;            // row group 0..3 (4 rows each)
    const int cg   = w & 1;             // col half 0..1 (12 cols each)
    const int rowbase = blockIdx.x * 16;

    // ---- issue ALL 32 A loads first (independent, fill the VMEM queue) ----
    const float* Xr0 = X + (rowbase + rg*4)*512 + lane;
    float pa[8][4];
    #pragma unroll
    for (int cny = 0; cny < 8; ++cny)
        #pragma unroll
        for (int r = 0; r < 4; ++r)
            pa[cny][r] = Xr0[cny*64 + r*512];

    // ---- stage W into LDS, coalesced: flat float2 loads, lanes
    //      consecutive (2-line span); magic div-3 for the LDS scatter ----
    {
        #pragma unroll
        for (int g = 0; g < 4; ++g) {
            const float* Wp = (g==0)?Wf:(g==1)?Wi:(g==2)?Wu:Wo;
            const float2* Wp2 = (const float2*)Wp;   // rows 0..511 = 1536 f2
            #pragma unroll
            for (int i = 0; i < 3; ++i) {
                int f = i*512 + tid;                  // 0..1535
                float2 v = Wp2[f];
                int k = (int)(((unsigned)f * 43691u) >> 17);  // f/3
                int cpair = f - k*3;                  // 0..2
                float* d = W_lds + k*25 + g*6 + cpair*2;
                d[0] = v.x; d[1] = v.y;
            }
        }
    }
    __syncthreads();   // vmcnt(0) drain: pays A latency once, here

    // ---- main loop: 8 chunks of 64 k, zero VMEM stalls ----
    v2f acc[4][6];
    #pragma unroll
    for (int r = 0; r < 4; ++r)
        #pragma unroll
        for (int p = 0; p < 6; ++p) acc[r][p] = (v2f){0.f, 0.f};

    const int colbase = cg*12;

    #pragma unroll
    for (int cny = 0; cny < 8; ++cny) {
        const float* Wrow = W_lds + (cny*64 + lane)*25 + colbase;
        float a0 = pa[cny][0], a1 = pa[cny][1], a2 = pa[cny][2], a3 = pa[cny][3];
        #pragma unroll
        for (int p = 0; p < 6; ++p) {
            float wa = Wrow[p];
            float wb = Wrow[p + 6];     // ds_read2_b32, conflict-free
            v2f wv = (v2f){wa, wb};
            acc[0][p] = __builtin_elementwise_fma((v2f){a0,a0}, wv, acc[0][p]);
            acc[1][p] = __builtin_elementwise_fma((v2f){a1,a1}, wv, acc[1][p]);
            acc[2][p] = __builtin_elementwise_fma((v2f){a2,a2}, wv, acc[2][p]);
            acc[3][p] = __builtin_elementwise_fma((v2f){a3,a3}, wv, acc[3][p]);
        }
    }

    // ---- quad reduction: static indexing only ----
    #pragma unroll
    for (int r = 0; r < 4; ++r)
        #pragma unroll
        for (int p = 0; p < 6; ++p) {
            float x = acc[r][p].x;
            x = dpp_add<0xB1>(x);
            x = dpp_add<0x4E>(x);
            acc[r][p].x = x;
            float y = acc[r][p].y;
            y = dpp_add<0xB1>(y);
            y = dpp_add<0x4E>(y);
            acc[r][p].y = y;
        }

    // flat v = r*12 + ph, ph = p + 6*e  ->  acc[v/12][v%6].{x if ph<6 else y}
    #define ACCV(v) ((((v) % 12) < 6) ? acc[(v)/12][(v)%6].x \
                                      : acc[(v)/12][(v)%6].y)
    const int j = lane & 3;
    const int q = lane >> 2;
    const bool j1 = (j & 1) != 0, j2 = (j & 2) != 0;
    float sel[12];
    #pragma unroll
    for (int i = 0; i < 12; ++i) {
        float c0 = ACCV(i*4 + 0), c1 = ACCV(i*4 + 1);
        float c2 = ACCV(i*4 + 2), c3 = ACCV(i*4 + 3);
        float lo = j1 ? c1 : c0;
        float hi = j1 ? c3 : c2;
        sel[i] = j2 ? hi : lo;
    }
    #undef ACCV

    __syncthreads();                    // everyone done reading W_lds
    #pragma unroll
    for (int i = 0; i < 12; ++i)
        W_lds[(w*48 + i*4 + j)*16 + q] = sel[i];
    __syncthreads();

    // ---- final: 384 outputs per block (8 waves * 4 rows * 12 cols) ----
    if (tid < 384) {
        int o = tid;
        int ww = o / 48, v = o - ww*48;
        int rr = v / 12, ph = v - rr*12;
        const float4* rp = (const float4*)(W_lds + (ww*48 + v)*16);
        float4 r0 = rp[0], r1 = rp[1], r2 = rp[2], r3 = rp[3];
        float s = ((r0.x+r0.y)+(r0.z+r0.w)) + ((r1.x+r1.y)+(r1.z+r1.w))
                + ((r2.x+r2.y)+(r2.z+r2.w)) + ((r3.x+r3.y)+(r3.z+r3.w));
        int col = (ww & 1)*12 + ph;
        int g = col / 6, jg = col - g*6;
        const float* bb = (g==0)?bf:(g==1)?bi:(g==2)?bu:bo;
        const float* tt = (g==0)?thf:(g==1)?thi:(g==2)?thu:tho;
        s += bb[jg] + tt[jg];
        int row = rowbase + (ww >> 1)*4 + rr;
        pre[row*24 + col] = s;
    }
}

__global__ __launch_bounds__(64, 1) void qlstm_scan(
    const float* __restrict__ pre,
    const float* __restrict__ Wf, const float* __restrict__ Wi,
    const float* __restrict__ Wu, const float* __restrict__ Wo,
    float* __restrict__ out)
{
    // 4 threads per batch element (one per gate), one aligned hw quad per batch.
    const int lane = threadIdx.x;
    const int bl   = lane >> 2;
    const int g    = lane & 3;
    const int b    = blockIdx.x * 16 + bl;

    const float* Wg = (g==0)?Wf:(g==1)?Wi:(g==2)?Wu:Wo;
    v2f Wh2[6][3];
    #pragma unroll
    for (int j = 0; j < 6; ++j)
        #pragma unroll
        for (int p = 0; p < 3; ++p)
            Wh2[j][p] = (v2f){Wg[(512 + j)*6 + 2*p], Wg[(512 + j)*6 + 2*p + 1]};

    // gate activation: act(z) = c0 + z*num(y)*rcp(den(y)), y=z^2, z in [-1,1]
    const float c0s = (g==2) ? 0.f  : 0.5f;
    const float n0s = (g==2) ? 15.f : 0.25f;
    const float n1s = (g==2) ? 1.f  : -0.020833333f;
    const float n2s = (g==2) ? 0.f  : 0.0020833333f;
    const float d0s = (g==2) ? 15.f : 1.f;
    const float d1s = (g==2) ? 6.f  : 0.f;
    const v2f c0v = (v2f){c0s, c0s}, n0v2 = (v2f){n0s, n0s};
    const v2f n1v2 = (v2f){n1s, n1s}, n2v2 = (v2f){n2s, n2s};
    const v2f d0v2 = (v2f){d0s, d0s}, d1v2 = (v2f){d1s, d1s};

    v2f h2[3], c2[3];
    #pragma unroll
    for (int p = 0; p < 3; ++p) { h2[p] = (v2f){0.f,0.f}; c2[p] = (v2f){0.f,0.f}; }

    // 2-step-deep prefetch of pre
    const float* pb = pre + b*24 + g*6;
    v2f x0 = *(const v2f*)(pb);
    v2f x1 = *(const v2f*)(pb + 2);
    v2f x2 = *(const v2f*)(pb + 4);
    v2f n0p = *(const v2f*)(pb + 256*24);
    v2f n1p = *(const v2f*)(pb + 256*24 + 2);
    v2f n2p = *(const v2f*)(pb + 256*24 + 4);

    for (int t = 0; t < 64; ++t) {
        v2f a2[3] = {x0, x1, x2};
        x0 = n0p; x1 = n1p; x2 = n2p;
        int tn = (t < 62) ? (t + 2) : 63;
        const float* pn = pre + (tn*256 + b)*24 + g*6;
        n0p = *(const v2f*)(pn);
        n1p = *(const v2f*)(pn + 2);
        n2p = *(const v2f*)(pn + 4);

        // a = xw + h@Wh via packed fma (18 v_pk_fma_f32)
        #pragma unroll
        for (int j = 0; j < 6; ++j) {
            float hs = (j&1) ? h2[j>>1].y : h2[j>>1].x;
            v2f hj = (v2f){hs, hs};
            #pragma unroll
            for (int p = 0; p < 3; ++p)
                a2[p] = __builtin_elementwise_fma(hj, Wh2[j][p], a2[p]);
        }

        float C[6];
        C[0] = __cosf(a2[0].x); C[1] = __cosf(a2[0].y);
        C[2] = __cosf(a2[1].x); C[3] = __cosf(a2[1].y);
        C[4] = __cosf(a2[2].x); C[5] = __cosf(a2[2].y);

        float p01 = C[0]*C[1], p23 = C[2]*C[3], p45 = C[4]*C[5];
        v2f zp[3];
        zp[0] = (v2f){C[1]*(p23*p45), p01};          // z0, z1
        zp[1] = (v2f){p01*C[2], p01*p23};            // z2, z3
        zp[2] = (v2f){zp[1].y*C[4], zp[1].y*p45};    // z4, z5

        // packed activation
        float act[6];
        #pragma unroll
        for (int p = 0; p < 3; ++p) {
            v2f y   = zp[p]*zp[p];
            v2f num = __builtin_elementwise_fma(y,
                        __builtin_elementwise_fma(y, n2v2, n1v2), n0v2);
            v2f den = __builtin_elementwise_fma(y, d1v2, d0v2);
            v2f r   = (v2f){fast_rcp(den.x), fast_rcp(den.y)};
            v2f av  = __builtin_elementwise_fma(zp[p]*num, r, c0v);
            act[2*p]   = av.x;
            act[2*p+1] = av.y;
        }

        // quad-broadcast exchange via DPP; repack as v2f
        v2f Fv[3], Iv[3], Uv[3], Ov[3];
        #pragma unroll
        for (int p = 0; p < 3; ++p) {
            Fv[p] = (v2f){quad_bcast<0>(act[2*p]), quad_bcast<0>(act[2*p+1])};
            Iv[p] = (v2f){quad_bcast<1>(act[2*p]), quad_bcast<1>(act[2*p+1])};
            Uv[p] = (v2f){quad_bcast<2>(act[2*p]), quad_bcast<2>(act[2*p+1])};
            Ov[p] = (v2f){quad_bcast<3>(act[2*p]), quad_bcast<3>(act[2*p+1])};
        }

        // packed LSTM update + tanh(c) Pade(5,4)
        #pragma unroll
        for (int p = 0; p < 3; ++p) {
            c2[p] = __builtin_elementwise_fma(Fv[p], c2[p], Iv[p]*Uv[p]);
            v2f y   = c2[p]*c2[p];
            v2f num = __builtin_elementwise_fma(y,
                        __builtin_elementwise_fma(y, (v2f){1.f,1.f}, (v2f){105.f,105.f}),
                        (v2f){945.f,945.f});
            v2f den = __builtin_elementwise_fma(y,
                        __builtin_elementwise_fma(y, (v2f){15.f,15.f}, (v2f){420.f,420.f}),
                        (v2f){945.f,945.f});
            v2f r   = (v2f){fast_rcp(den.x), fast_rcp(den.y)};
            h2[p] = Ov[p]*(c2[p]*num*r);
        }

        if (g < 3) {
            v2f lo = (g==1) ? h2[1] : h2[0];
            v2f v  = (g==2) ? h2[2] : lo;
            *(v2f*)(out + (t*256 + b)*6 + g*2) = v;
        }
    }

    if (g < 3) {
        v2f lo = (g==1) ? h2[1] : h2[0];
        v2f v  = (g==2) ? h2[2] : lo;
        *(v2f*)(out + 64*256*6 + b*6 + g*2) = v;
        v2f lo2 = (g==1) ? c2[1] : c2[0];
        v2f u   = (g==2) ? c2[2] : lo2;
        *(v2f*)(out + 64*256*6 + 256*6 + b*6 + g*2) = u;
    }
}

extern "C" void kernel_launch(void* const* d_in, const int* in_sizes, int n_in,
                              void* d_out, int out_size, void* d_ws, size_t ws_size,
                              hipStream_t stream) {
    const float* X   = (const float*)d_in[0];
    const float* Wf  = (const float*)d_in[1];
    const float* bf_ = (const float*)d_in[2];
    const float* Wi  = (const float*)d_in[3];
    const float* bi_ = (const float*)d_in[4];
    const float* Wu  = (const float*)d_in[5];
    const float* bu_ = (const float*)d_in[6];
    const float* Wo  = (const float*)d_in[7];
    const float* bo_ = (const float*)d_in[8];
    const float* thf = (const float*)d_in[9];
    const float* thi = (const float*)d_in[10];
    const float* thu = (const float*)d_in[11];
    const float* tho = (const float*)d_in[12];

    float* pre = (float*)d_ws;           // 16384*24 floats = 1.57 MB
    float* out = (float*)d_out;

    gemm_pre<<<1024, 512, 0, stream>>>(X, Wf, bf_, Wi, bi_, Wu, bu_, Wo, bo_,
                                       thf, thi, thu, tho, pre);
    qlstm_scan<<<16, 64, 0, stream>>>(pre, Wf, Wi, Wu, Wo, out);
}